// Round 4
// baseline (50.787 us; speedup 1.0000x reference)
//
#include <hip/hip_runtime.h>
#include <math.h>

#define NPART 8192
#define R2c   0.0025f     /* RADIUS^2 (float32(0.05^2)) */
#define CR2c  0.01f       /* (2*RADIUS)^2 */
#define ACCS  0.005f
#define MAXV  0.05f
#define EPSV  1e-06f
#define NB1D  20          /* bins per axis, width 0.1 over [-1,1] */
#define NBINS 400
#define SWBLK 2048        /* sweep blocks: 4 waves = 4 sorted slots each */
#define OUT_SCALARS 57344 /* offset of the 6 scalar outputs in d_out */

#define WRED(v) do { \
    v += __shfl_xor(v, 32); v += __shfl_xor(v, 16); v += __shfl_xor(v, 8); \
    v += __shfl_xor(v, 4);  v += __shfl_xor(v, 2);  v += __shfl_xor(v, 1); \
  } while (0)

// ---------------------------------------------------------------- prep ----
// Per row: 32B record {px,py,y0,y1 | y2,y3,ci,orig} + bin id.
__global__ __launch_bounds__(256) void prep_kernel(
    const float* __restrict__ x, const float* __restrict__ wn,
    float4* __restrict__ rec, int* __restrict__ binid)
{
  int i = blockIdx.x * 256 + threadIdx.x;
  const float* xi = x + i * 7;
  float v0 = xi[0], v1 = xi[1], v2 = xi[2], v3 = xi[3];
  float v4 = xi[4], v5 = xi[5], v6 = xi[6];
  float ci = (v4 > 0.5f) ? 1.0f : 0.0f;
  float y[4];
#pragma unroll
  for (int c = 0; c < 4; ++c) {
    float s = v0 * wn[c];
    s += v1 * wn[4 + c];
    s += v2 * wn[8 + c];
    s += v3 * wn[12 + c];
    s += v4 * wn[16 + c];
    s += v5 * wn[20 + c];
    s += v6 * wn[24 + c];
    y[c] = s;
  }
  int bx = (int)floorf((v0 + 1.0f) * 10.0f); bx = bx < 0 ? 0 : (bx > 19 ? 19 : bx);
  int by = (int)floorf((v1 + 1.0f) * 10.0f); by = by < 0 ? 0 : (by > 19 ? 19 : by);
  binid[i] = by * NB1D + bx;
  rec[i * 2]     = make_float4(v0, v1, y[0], y[1]);
  rec[i * 2 + 1] = make_float4(y[2], y[3], ci, __int_as_float(i));
}

// ---------------------------------------------------------------- hist ----
// One block: LDS histogram (order-independent counts) + inclusive scan ->
// binstart[0..NBINS] (exclusive prefix, binstart[NBINS]=NPART). Deterministic.
__global__ __launch_bounds__(1024) void hist_kernel(
    const int* __restrict__ binid, int* __restrict__ binstart)
{
  __shared__ int h[NBINS];
  __shared__ int sc[512];
  int t = threadIdx.x;
  if (t < NBINS) h[t] = 0;
  __syncthreads();
#pragma unroll
  for (int k = 0; k < 8; ++k) atomicAdd(&h[binid[k * 1024 + t]], 1);
  __syncthreads();
  if (t < 512) sc[t] = (t < NBINS) ? h[t] : 0;
  __syncthreads();
  for (int off = 1; off < 512; off <<= 1) {
    int v = 0, u = 0;
    if (t < 512) { v = sc[t]; u = (t >= off) ? sc[t - off] : 0; }
    __syncthreads();
    if (t < 512) sc[t] = v + u;
    __syncthreads();
  }
  if (t < NBINS) binstart[t + 1] = sc[t];
  if (t == 0) binstart[0] = 0;
}

// -------------------------------------------------------------- scatter ---
// Stable counting-sort scatter: one wave per bin scans binid[] in index
// order; ballot + prefix-popcount gives the stable rank. Fully deterministic.
// 4 chunks per iteration so 4 loads are in flight (few waves/CU here).
__global__ __launch_bounds__(256) void scatter_kernel(
    const int* __restrict__ binid, const int* __restrict__ binstart,
    const float4* __restrict__ rec, float4* __restrict__ srec)
{
  int lane = threadIdx.x & 63, wave = threadIdx.x >> 6;
  int b = blockIdx.x * 4 + wave;
  int rank = binstart[b];
  for (int c = 0; c < NPART; c += 256) {
    int i0 = binid[c + lane];
    int i1 = binid[c + 64 + lane];
    int i2 = binid[c + 128 + lane];
    int i3 = binid[c + 192 + lane];
#define STEP(II, CC) { \
      unsigned long long m = __ballot((II) == b); \
      if ((II) == b) { \
        int my = rank + __popcll(m & ((1ull << lane) - 1ull)); \
        srec[my * 2]     = rec[((CC) + lane) * 2]; \
        srec[my * 2 + 1] = rec[((CC) + lane) * 2 + 1]; \
      } \
      rank += __popcll(m); }
    STEP(i0, c) STEP(i1, c + 64) STEP(i2, c + 128) STEP(i3, c + 192)
#undef STEP
  }
}

// --------------------------------------------------------------- sweep ----
// One wave per sorted slot (8192 waves, fully co-resident at 8 waves/SIMD).
// Candidates = 3 contiguous sorted segments (3x3 bin neighborhood), ~184
// total -> ~3-6 branchless chunk iterations. Self excluded via index compare
// (exact). dist2 in the reference's non-contracted mul/mul/add form.
__global__ __launch_bounds__(256, 8) void sweep_kernel(
    const float* __restrict__ x, const float* __restrict__ wself,
    const float* __restrict__ bvec, const int* __restrict__ binid,
    const int* __restrict__ binstart, const float4* __restrict__ srec,
    float* __restrict__ out, float* __restrict__ partials)
{
  __shared__ float s_scal[4][6];
  const int lane = threadIdx.x & 63, wave = threadIdx.x >> 6;
  const int s = blockIdx.x * 4 + wave;
  const float4 r0 = srec[s * 2];
  const float4 r1 = srec[s * 2 + 1];
  const float px = r0.x, py = r0.y, ci = r1.z;
  const int orig = __float_as_int(r1.w);
  const int bid = binid[orig];
  const int bx = bid % NB1D, by = bid / NB1D;
  const int xlo = (bx > 0) ? bx - 1 : 0, xhi = (bx < 19) ? bx + 1 : 19;
  const int ylo = (by > 0) ? by - 1 : 0, yhi = (by < 19) ? by + 1 : 19;

  float nsx = 0.f, nsy = 0.f, nsz = 0.f, nsw = 0.f;
  float cntR = 0.f, cnbR = 0.f, consCR = 0.f;

  for (int yy = ylo; yy <= yhi; ++yy) {
    const int beg = binstart[yy * NB1D + xlo];
    const int end = binstart[yy * NB1D + xhi + 1];
    for (int c = beg; c < end; c += 64) {
      int idx = c + lane;
      bool inr = idx < end;
      int ia = inr ? idx : beg;
      float4 a0 = srec[ia * 2];
      float4 a1 = srec[ia * 2 + 1];
      float dx = __fsub_rn(px, a0.x), dy = __fsub_rn(py, a0.y);
      float d2 = __fadd_rn(__fmul_rn(dx, dx), __fmul_rn(dy, dy));
      bool valid = inr && (__float_as_int(a1.w) != orig);
      bool inCR = valid && (d2 < CR2c);
      bool inR  = valid && (d2 < R2c);
      float cj = a1.z;
      consCR += inCR ? cj : 0.f;
      cntR += inR ? 1.f : 0.f;
      cnbR += inR ? cj : 0.f;
      nsx += inR ? a0.z : 0.f;
      nsy += inR ? a0.w : 0.f;
      nsz += inR ? a1.x : 0.f;
      nsw += inR ? a1.y : 0.f;
    }
  }

  WRED(nsx); WRED(nsy); WRED(nsz); WRED(nsw);
  WRED(cntR); WRED(cnbR); WRED(consCR);

  if (lane == 0) {
    const float* xi = x + orig * 7;
    float vx = xi[2], vy = xi[3], typ = xi[4], x5 = xi[5], x6 = xi[6];
    float h0 = bvec[0] + px * wself[0] + py * wself[4] + vx * wself[8] +
               vy * wself[12] + typ * wself[16] + x5 * wself[20] +
               x6 * wself[24] + nsx;
    float h1 = bvec[1] + px * wself[1] + py * wself[5] + vx * wself[9] +
               vy * wself[13] + typ * wself[17] + x5 * wself[21] +
               x6 * wself[25] + nsy;
    float h2 = bvec[2] + px * wself[2] + py * wself[6] + vx * wself[10] +
               vy * wself[14] + typ * wself[18] + x5 * wself[22] +
               x6 * wself[26] + nsz;
    float h3 = bvec[3] + px * wself[3] + py * wself[7] + vx * wself[11] +
               vy * wself[15] + typ * wself[19] + x5 * wself[23] +
               x6 * wself[27] + nsw;
    float scm = ACCS * ci;
    h0 *= scm; h1 *= scm; h2 *= scm; h3 *= scm;
    float nvx = fminf(fmaxf(vx + h0, -MAXV), MAXV);
    float nvy = fminf(fmaxf(vy + h1, -MAXV), MAXV);
    float npx = px + nvx, npy = py + nvy;
    float border = 0.f;
    float ax = fabsf(npx), ay = fabsf(npy);
    if (ax > 1.0f) border += logf(ax + EPSV);
    if (ay > 1.0f) border += logf(ay + EPSV);
    bool dead = (ci > 0.5f) && (cnbR < 2.5f);
    bool consumed = (ci < 0.5f) && (consCR > 4.5f);
    float keep = (dead || consumed) ? 0.f : 1.f;
    float* orow = out + (size_t)orig * 7;
    orow[0] = npx * keep; orow[1] = npy * keep;
    orow[2] = nvx * keep; orow[3] = nvy * keep;
    orow[4] = typ * keep; orow[5] = h2 * keep; orow[6] = h3 * keep;
    s_scal[wave][0] = fabsf(nvx);
    s_scal[wave][1] = fabsf(nvy);
    s_scal[wave][2] = border;
    s_scal[wave][3] = consumed ? 1.f : 0.f;
    s_scal[wave][4] = dead ? 1.f : 0.f;
    s_scal[wave][5] = cntR - cnbR;
  }
  __syncthreads();
  if (threadIdx.x == 0) {
#pragma unroll
    for (int k = 0; k < 6; ++k)
      partials[blockIdx.x * 6 + k] =
          s_scal[0][k] + s_scal[1][k] + s_scal[2][k] + s_scal[3][k];
  }
}

// ------------------------------------------------------------- reduce -----
__global__ __launch_bounds__(384) void reduce_kernel(
    const float* __restrict__ partials, float* __restrict__ out)
{
  int wave = threadIdx.x >> 6, lane = threadIdx.x & 63;
  if (wave >= 6) return;
  float s = 0.f;
  for (int bidx = lane; bidx < SWBLK; bidx += 64) s += partials[bidx * 6 + wave];
  WRED(s);
  if (lane == 0) {
    float v = s;
    if (wave < 2) v = s * (1.0f / 8192.0f); /* vel_bonus = mean */
    out[OUT_SCALARS + wave] = v;
  }
}

// ------------------------------------------------------------- launch -----
extern "C" void kernel_launch(void* const* d_in, const int* in_sizes, int n_in,
                              void* d_out, int out_size, void* d_ws, size_t ws_size,
                              hipStream_t stream)
{
  const float* x      = (const float*)d_in[0];
  const float* wself  = (const float*)d_in[1];
  const float* wneigh = (const float*)d_in[2];
  const float* bvec   = (const float*)d_in[3];
  float* out = (float*)d_out;
  float* ws  = (float*)d_ws;

  float4* rec   = (float4*)ws;                      /* 8N floats  */
  float4* srec  = (float4*)(ws + 8 * NPART);        /* 8N floats  */
  int* binid    = (int*)(ws + 16 * NPART);          /* N ints     */
  int* binstart = (int*)(ws + 17 * NPART);          /* 401 ints   */
  float* partials = ws + 17 * NPART + 512;          /* SWBLK*6    */

  hipLaunchKernelGGL(prep_kernel, dim3(NPART / 256), dim3(256), 0, stream,
                     x, wneigh, rec, binid);
  hipLaunchKernelGGL(hist_kernel, dim3(1), dim3(1024), 0, stream,
                     binid, binstart);
  hipLaunchKernelGGL(scatter_kernel, dim3(NBINS / 4), dim3(256), 0, stream,
                     binid, binstart, rec, srec);
  hipLaunchKernelGGL(sweep_kernel, dim3(SWBLK), dim3(256), 0, stream,
                     x, wself, bvec, binid, binstart, srec, out, partials);
  hipLaunchKernelGGL(reduce_kernel, dim3(1), dim3(384), 0, stream,
                     partials, out);
}